// Round 1
// baseline (1025.065 us; speedup 1.0000x reference)
//
#include <hip/hip_runtime.h>
#include <math.h>

// Problem constants (from reference)
#define UNITS    256
#define NUM_GROUPS 64
#define FEATURES 256
#define BATCH    2048

// C = log(expm1(1.0))
#define SOFTPLUS_C 0.5413248546129181f

// Numerically stable softplus: log1p(exp(z)) = max(z,0) + log1p(exp(-|z|))
__device__ __forceinline__ float softplus_f(float z) {
    return fmaxf(z, 0.0f) + log1pf(expf(-fabsf(z)));
}

__global__ __launch_bounds__(256)
void mld_kernel(const float* __restrict__ x,        // [B, P]
                const int*   __restrict__ gid,      // [B]
                const float* __restrict__ w_mu,     // [G, U, P]
                const float* __restrict__ w_sigma,  // [G, U, P]
                const float* __restrict__ b_mu,     // [G, U]
                const float* __restrict__ b_sigma,  // [G, U]
                const float* __restrict__ eps_w,    // [B, U, P]
                const float* __restrict__ eps_b,    // [B, U]
                float*       __restrict__ out) {    // [B, U]
    const int lane   = threadIdx.x & 63;
    const int wid    = (int)((blockIdx.x * blockDim.x + threadIdx.x) >> 6);
    const int nwaves = (int)((gridDim.x * blockDim.x) >> 6);
    const int total  = BATCH * UNITS;

    for (int o = wid; o < total; o += nwaves) {
        const int B = o >> 8;        // o / UNITS
        const int u = o & 255;       // o % UNITS
        const int g = gid[B];

        const int p0 = lane << 2;    // 4 floats per lane -> 256 covered by 64 lanes

        const size_t row_ep = (size_t)o * FEATURES + p0;                 // eps_w row
        const size_t row_w  = ((size_t)g * UNITS + u) * FEATURES + p0;   // param row
        const size_t row_x  = (size_t)B * FEATURES + p0;                 // x row

        const float4 ep = *reinterpret_cast<const float4*>(eps_w   + row_ep);
        const float4 xv = *reinterpret_cast<const float4*>(x       + row_x);
        const float4 mu = *reinterpret_cast<const float4*>(w_mu    + row_w);
        const float4 sg = *reinterpret_cast<const float4*>(w_sigma + row_w);

        float acc;
        acc  = (mu.x + softplus_f(SOFTPLUS_C + sg.x) * ep.x) * xv.x;
        acc += (mu.y + softplus_f(SOFTPLUS_C + sg.y) * ep.y) * xv.y;
        acc += (mu.z + softplus_f(SOFTPLUS_C + sg.z) * ep.z) * xv.z;
        acc += (mu.w + softplus_f(SOFTPLUS_C + sg.w) * ep.w) * xv.w;

        // 64-lane butterfly reduction
        #pragma unroll
        for (int off = 32; off > 0; off >>= 1)
            acc += __shfl_xor(acc, off, 64);

        if (lane == 0) {
            const int gu = g * UNITS + u;
            const float bias = b_mu[gu] + softplus_f(SOFTPLUS_C + b_sigma[gu]) * eps_b[o];
            out[o] = acc + bias;
        }
    }
}

extern "C" void kernel_launch(void* const* d_in, const int* in_sizes, int n_in,
                              void* d_out, int out_size, void* d_ws, size_t ws_size,
                              hipStream_t stream) {
    const float* x       = (const float*)d_in[0];
    const int*   gid     = (const int*)  d_in[1];
    const float* w_mu    = (const float*)d_in[2];
    const float* w_sigma = (const float*)d_in[3];
    const float* b_mu    = (const float*)d_in[4];
    const float* b_sigma = (const float*)d_in[5];
    const float* eps_w   = (const float*)d_in[6];
    const float* eps_b   = (const float*)d_in[7];
    float* out = (float*)d_out;

    // 2048 blocks x 256 threads = 8192 waves; 524288 outputs -> 64 iters/wave
    mld_kernel<<<2048, 256, 0, stream>>>(x, gid, w_mu, w_sigma, b_mu, b_sigma,
                                         eps_w, eps_b, out);
}